// Round 5
// baseline (169.956 us; speedup 1.0000x reference)
//
#include <hip/hip_runtime.h>
#include <hip/hip_bf16.h>
#include <stdint.h>
#include <stddef.h>

#define S_LEN 2048
#define DMODEL 1024
#define NHEAD 16
#define HDIM 64
#define BATCH 2
#define MROWS (BATCH * S_LEN) /* 4096 */
#define QKV_LD 3072

typedef unsigned short u16;
typedef __attribute__((ext_vector_type(8))) short bf16x8;
typedef __attribute__((ext_vector_type(4))) float f32x4;

__device__ inline u16 f32_to_bf16(float f) {
  union { float f; unsigned int u; } v; v.f = f;
  unsigned int u = v.u;
  unsigned int r = (u + 0x7fffu + ((u >> 16) & 1u)) >> 16;
  return (u16)r;
}

__device__ inline void gload16(const u16* g, u16* l) {
  __builtin_amdgcn_global_load_lds(
      (const __attribute__((address_space(1))) unsigned int*)g,
      (__attribute__((address_space(3))) unsigned int*)l, 16, 0, 0);
}

// ---------------- fused prologue: conv + window + W-transpose + Wc build ----------------
// Max static LDS = 32x33 f32 = 4.2 KiB -> occupancy is wave-capped (8 blocks/CU),
// not LDS-capped. (R4 post-mortem: 64 KiB LDS here cost 35 us.)
// blocks [0,2048): x->bf16 ; 2048: window ; [2049,5121): transpose ; [5121,5185): Wc
__global__ __launch_bounds__(256) void prep(const float* __restrict__ x, u16* __restrict__ xb,
                                            const float* __restrict__ alpha, int* __restrict__ halfw,
                                            const float* __restrict__ Wq, const float* __restrict__ Wk,
                                            const float* __restrict__ Wv, u16* __restrict__ Wt,
                                            const float* __restrict__ W_o, const float* __restrict__ Wfc,
                                            u16* __restrict__ Wc_t) {
  __shared__ float lds[32 * 33]; // 4224 B
  const int bid = blockIdx.x, tid = threadIdx.x;

  if (bid < 2048) {
    // ---- x -> bf16 ----
    size_t i = ((size_t)bid * 256 + tid) * 8;
    float4 v0 = *(const float4*)(x + i);
    float4 v1 = *(const float4*)(x + i + 4);
    bf16x8 r;
    r[0] = (short)f32_to_bf16(v0.x); r[1] = (short)f32_to_bf16(v0.y);
    r[2] = (short)f32_to_bf16(v0.z); r[3] = (short)f32_to_bf16(v0.w);
    r[4] = (short)f32_to_bf16(v1.x); r[5] = (short)f32_to_bf16(v1.y);
    r[6] = (short)f32_to_bf16(v1.z); r[7] = (short)f32_to_bf16(v1.w);
    *(bf16x8*)(xb + i) = r;
  } else if (bid == 2048) {
    // ---- dynamic window size ----
    float s = 0.f;
    for (int i = tid; i < BATCH * DMODEL; i += 256) {
      int b = i >> 10, d = i & 1023;
      size_t base = (size_t)b * S_LEN * DMODEL + d;
      float f1 = x[base + (size_t)(S_LEN - 1) * DMODEL];
      float f0 = x[base + (size_t)(S_LEN - 2) * DMODEL];
      s += fabsf(f1 - f0);
    }
#pragma unroll
    for (int m = 32; m >= 1; m >>= 1) s += __shfl_xor(s, m, 64);
    if ((tid & 63) == 0) lds[tid >> 6] = s;
    __syncthreads();
    if (tid == 0) {
      float total = lds[0] + lds[1] + lds[2] + lds[3];
      float mean = total / (float)(BATCH * DMODEL);
      float e1 = x[(size_t)(S_LEN - 1) * DMODEL];
      float e0 = x[(size_t)(S_LEN - 2) * DMODEL];
      float ew = fabsf(e1 - e0);
      float a = 1.f / (1.f + expf(-alpha[0]));
      float sig = a * mean + (1.f - a) * ew;
      float scale = 1.f / (1.f + expf(-sig));
      int wv = (int)floorf(24.f + 96.f * scale);
      *halfw = wv >> 1;
    }
  } else if (bid < 2049 + 3072) {
    // ---- transpose Wq/Wk/Wv -> bf16 [3][N][K] ----
    float (*tile)[33] = (float (*)[33])lds;
    const int r = bid - 2049;
    const int z = r >> 10, rem = r & 1023;
    const int k0 = (rem >> 5) * 32, n0 = (rem & 31) * 32;
    const float* W = z == 0 ? Wq : (z == 1 ? Wk : Wv);
    const int tx = tid & 31, ty = tid >> 5;
#pragma unroll
    for (int i = 0; i < 4; ++i)
      tile[ty + i * 8][tx] = W[(size_t)(k0 + ty + i * 8) * DMODEL + n0 + tx];
    __syncthreads();
    u16* o = Wt + (size_t)z * DMODEL * DMODEL;
#pragma unroll
    for (int i = 0; i < 4; ++i)
      o[(size_t)(n0 + ty + i * 8) * DMODEL + k0 + tx] = f32_to_bf16(tile[tx][ty + i * 8]);
  } else {
    // ---- Wc = blockdiag(W_o) @ Wfc, transposed bf16 [N][K]; zero-LDS streaming.
    // Wfc load: coalesced across tx, each value read once (no reuse -> no staging).
    // W_o operand: wave-uniform index -> scalar loads/broadcast.
    const int idx = bid - 5121;       // 0..63
    const int nb = idx & 3, h = idx >> 2;
    const int n0 = nb * 256;
    float acc[64];
#pragma unroll
    for (int d = 0; d < 64; ++d) acc[d] = 0.f;
#pragma unroll 4
    for (int c = 0; c < 64; ++c) {
      float wv = Wfc[(size_t)(h * 64 + c) * DMODEL + n0 + tid];
#pragma unroll
      for (int d = 0; d < 64; ++d)
        acc[d] += W_o[(size_t)(h * 64 + d) * 64 + c] * wv;
    }
    u16 tmp[64];
#pragma unroll
    for (int d = 0; d < 64; ++d) tmp[d] = f32_to_bf16(acc[d]);
    u16* dst = Wc_t + (size_t)(n0 + tid) * DMODEL + h * 64;
#pragma unroll
    for (int q = 0; q < 8; ++q)
      *(bf16x8*)(dst + q * 8) = *(bf16x8*)(tmp + q * 8);
  }
}

// ---------------- QKV GEMM: 256x192, BK=64, 8 waves, counted-vmcnt 4-phase ----------------
#define G1_ASZ (256 * 64) /* u16 elems */
#define G1_BSZ (192 * 64)
__global__ __launch_bounds__(512, 2) void gemm_qkv(
    const u16* __restrict__ A, const u16* __restrict__ Bt,
    const float* __restrict__ bq, const float* __restrict__ bk,
    const float* __restrict__ bv, u16* __restrict__ out) {
  __shared__ __align__(16) u16 smem[2][G1_ASZ + G1_BSZ]; // 112 KiB

  const int tid = threadIdx.x;
  const int l = tid & 63, w = tid >> 6;   // 8 waves
  const int wr = w >> 2, wc = w & 3;      // 2 x 4; wave tile 128x48
  const int lrow = l & 15, lk = l >> 4;

  // bn-major bijective XCD swizzle (grid 256): per-XCD B slice 768 KB, L2-resident
  const int xcd = blockIdx.x & 7;
  const int idx = blockIdx.x >> 3;
  const int bm = idx & 15;
  const int bn = xcd * 2 + (idx >> 4);
  const int rowA0 = bm * 256;
  const int colB0 = bn * 192;

  f32x4 acc[8][3] = {};

  auto stage = [&](int buf, int kt) {   // 7 gload16 per thread
    u16* As = smem[buf];
    u16* Bs = smem[buf] + G1_ASZ;
#pragma unroll
    for (int i = 0; i < 4; ++i) {
      int c = i * 512 + tid;
      int row = c >> 3, u = c & 7;
      const u16* g = A + (size_t)(rowA0 + row) * DMODEL + kt + ((u ^ (row & 7)) << 3);
      gload16(g, As + c * 8);
    }
#pragma unroll
    for (int i = 0; i < 3; ++i) {
      int c = i * 512 + tid;
      int row = c >> 3, u = c & 7;
      const u16* g = Bt + (size_t)(colB0 + row) * DMODEL + kt + ((u ^ (row & 7)) << 3);
      gload16(g, Bs + c * 8);
    }
  };

  stage(0, 0);

  int buf = 0;
#pragma unroll 1
  for (int t = 0; t < 16; ++t) {
    if (t < 15) {
      stage(buf ^ 1, (t + 1) * 64);
      asm volatile("s_waitcnt vmcnt(7)" ::: "memory");  // tile t landed; t+1 in flight
    } else {
      asm volatile("s_waitcnt vmcnt(0)" ::: "memory");
    }
    __builtin_amdgcn_s_barrier();
    asm volatile("" ::: "memory");      // no LDS-read hoisting above the barrier

    const u16* As = smem[buf];
    const u16* Bs = smem[buf] + G1_ASZ;
#pragma unroll
    for (int kk = 0; kk < 2; ++kk) {
      const int ksw = ((kk << 2) + lk);
      const int swz = ((ksw ^ (lrow & 7)) << 3);
      bf16x8 bg[3];
#pragma unroll
      for (int n = 0; n < 3; ++n) {
        int r = wc * 48 + n * 16 + lrow;
        bg[n] = *(const bf16x8*)(Bs + r * 64 + swz);
      }
#pragma unroll
      for (int mh = 0; mh < 2; ++mh) {
        bf16x8 af[4];
#pragma unroll
        for (int i = 0; i < 4; ++i) {
          int r = wr * 128 + (mh * 4 + i) * 16 + lrow;
          af[i] = *(const bf16x8*)(As + r * 64 + swz);
        }
        __builtin_amdgcn_s_setprio(1);
#pragma unroll
        for (int i = 0; i < 4; ++i)
#pragma unroll
          for (int n = 0; n < 3; ++n)
            acc[mh * 4 + i][n] =
                __builtin_amdgcn_mfma_f32_16x16x32_bf16(af[i], bg[n], acc[mh * 4 + i][n], 0, 0, 0);
        __builtin_amdgcn_s_setprio(0);
        __builtin_amdgcn_s_barrier();   // phase alignment; doubles as tile boundary on last phase
      }
    }
    asm volatile("" ::: "memory");
    buf ^= 1;
  }

  // epilogue: per-column bias; q columns also folded by 1/8
#pragma unroll
  for (int n = 0; n < 3; ++n) {
    int c = colB0 + wc * 48 + n * 16 + lrow;   // 0..3071
    float bias = (c < 1024) ? bq[c] : ((c < 2048) ? bk[c - 1024] : bv[c - 2048]);
    float mult = (c < 1024) ? 0.125f : 1.0f;
#pragma unroll
    for (int m = 0; m < 8; ++m) {
      int r0 = rowA0 + wr * 128 + m * 16 + lk * 4;
#pragma unroll
      for (int j = 0; j < 4; ++j)
        out[(size_t)(r0 + j) * QKV_LD + c] = f32_to_bf16((acc[m][n][j] + bias) * mult);
    }
  }
}

// ---------------- final FC GEMM: 128x128, BK=64, 4 waves, counted-vmcnt 2-phase ----------------
__global__ __launch_bounds__(256) void gemm_fc(const u16* __restrict__ A,
                                               const u16* __restrict__ Bt,
                                               const float* __restrict__ bias,
                                               float* __restrict__ out) {
  __shared__ __align__(16) u16 smem[2][256 * 64]; // 64 KiB

  const int tid = threadIdx.x;
  const int l = tid & 63, w = tid >> 6;   // 4 waves, 2x2
  const int wr = w >> 1, wc = w & 1;
  const int lrow = l & 15, lk = l >> 4;

  const int bn = blockIdx.x & 7;
  const int bm = blockIdx.x >> 3;
  const int rowA0 = bm * 128, colB0 = bn * 128;

  f32x4 acc[4][4] = {};

  auto stage = [&](int buf, int kt) {   // 8 gload16 per thread
    u16* As = smem[buf];
    u16* Bs = smem[buf] + 128 * 64;
#pragma unroll
    for (int i = 0; i < 4; ++i) {
      int c = i * 256 + tid;
      int row = c >> 3, u = c & 7;
      const u16* g = A + (size_t)(rowA0 + row) * DMODEL + kt + ((u ^ (row & 7)) << 3);
      gload16(g, As + c * 8);
    }
#pragma unroll
    for (int i = 0; i < 4; ++i) {
      int c = i * 256 + tid;
      int row = c >> 3, u = c & 7;
      const u16* g = Bt + (size_t)(colB0 + row) * DMODEL + kt + ((u ^ (row & 7)) << 3);
      gload16(g, Bs + c * 8);
    }
  };

  stage(0, 0);

  int buf = 0;
#pragma unroll 1
  for (int t = 0; t < 16; ++t) {
    if (t < 15) {
      stage(buf ^ 1, (t + 1) * 64);
      asm volatile("s_waitcnt vmcnt(8)" ::: "memory");
    } else {
      asm volatile("s_waitcnt vmcnt(0)" ::: "memory");
    }
    __builtin_amdgcn_s_barrier();
    asm volatile("" ::: "memory");

    const u16* As = smem[buf];
    const u16* Bs = smem[buf] + 128 * 64;
#pragma unroll
    for (int kk = 0; kk < 2; ++kk) {
      const int swz = ((((kk << 2) + lk) ^ (lrow & 7)) << 3);
      bf16x8 af[4], bg[4];
#pragma unroll
      for (int m = 0; m < 4; ++m) {
        int r = wr * 64 + m * 16 + lrow;
        af[m] = *(const bf16x8*)(As + r * 64 + swz);
      }
#pragma unroll
      for (int n = 0; n < 4; ++n) {
        int r = wc * 64 + n * 16 + lrow;
        bg[n] = *(const bf16x8*)(Bs + r * 64 + swz);
      }
      __builtin_amdgcn_s_setprio(1);
#pragma unroll
      for (int m = 0; m < 4; ++m)
#pragma unroll
        for (int n = 0; n < 4; ++n)
          acc[m][n] = __builtin_amdgcn_mfma_f32_16x16x32_bf16(af[m], bg[n], acc[m][n], 0, 0, 0);
      __builtin_amdgcn_s_setprio(0);
      __builtin_amdgcn_s_barrier();
    }
    asm volatile("" ::: "memory");
    buf ^= 1;
  }

#pragma unroll
  for (int n = 0; n < 4; ++n) {
    int c = colB0 + wc * 64 + n * 16 + lrow;
    float bv = bias[c];
#pragma unroll
    for (int m = 0; m < 4; ++m) {
      int r0 = rowA0 + wr * 64 + m * 16 + lk * 4;
#pragma unroll
      for (int j = 0; j < 4; ++j)
        out[(size_t)(r0 + j) * DMODEL + c] = acc[m][n][j] + bv;
    }
  }
}

// ---------------- banded attention: 64 queries x 192 keys per block ----------------
__global__ __launch_bounds__(256) void attn_win(const u16* __restrict__ qkv,
                                                u16* __restrict__ ao,
                                                const int* __restrict__ halfptr) {
  __shared__ __align__(16) u16 KP[12800];  // K [192][64] swizzled; reused as P [64][200]
  __shared__ __align__(16) u16 Vt[64 * 200]; // V transposed [d][key]
  const int tid = threadIdx.x, l = tid & 63, w = tid >> 6;
  const int lrow = l & 15, lk = l >> 4;
  const int q0 = blockIdx.x * 64, k0 = q0 - 64;
  const int h = blockIdx.y, b = blockIdx.z;
  const int halfw = *halfptr;

  const u16* qb = qkv;
  const u16* kb = qkv + 1024;
  const u16* vb = qkv + 2048;

  // K stage via global_load_lds (pre-swizzled source, linear dest). Out-of-band
  // rows read valid ws memory (finite garbage) and are always masked below.
#pragma unroll
  for (int i = 0; i < 6; ++i) {
    int c = i * 256 + tid;
    int row = c >> 3, u = c & 7;
    const u16* g = kb + (ptrdiff_t)((b * S_LEN + k0 + row) * QKV_LD + h * 64 + ((u ^ (row & 7)) << 3));
    gload16(g, KP + c * 8);
  }
  const int qrow = q0 + w * 16 + lrow;
  bf16x8 qf[2];
#pragma unroll
  for (int kk = 0; kk < 2; ++kk)
    qf[kk] = *(const bf16x8*)(qb + (ptrdiff_t)((b * S_LEN + qrow) * QKV_LD + h * 64 + kk * 32 + lk * 8));
  bf16x8 vreg[6];
#pragma unroll
  for (int i = 0; i < 6; ++i) {
    int c = i * 256 + tid;
    int row = c % 192, ch = c / 192;
    vreg[i] = *(const bf16x8*)(vb + (ptrdiff_t)((b * S_LEN + k0 + row) * QKV_LD + h * 64 + ch * 8));
  }

  asm volatile("s_waitcnt vmcnt(0)" ::: "memory");
  __syncthreads();

  f32x4 sc[12];
#pragma unroll
  for (int f = 0; f < 12; ++f) sc[f] = (f32x4){0.f, 0.f, 0.f, 0.f};
#pragma unroll
  for (int kk = 0; kk < 2; ++kk) {
#pragma unroll
    for (int f = 0; f < 12; ++f) {
      bf16x8 kf = *(const bf16x8*)(KP + (f * 16 + lrow) * 64 + ((((kk << 2) + lk) ^ (lrow & 7)) << 3));
      sc[f] = __builtin_amdgcn_mfma_f32_16x16x32_bf16(qf[kk], kf, sc[f], 0, 0, 0);
    }
  }

#pragma unroll
  for (int i = 0; i < 6; ++i) {
    int c = i * 256 + tid;
    int row = c % 192, ch = c / 192;
#pragma unroll
    for (int e = 0; e < 8; ++e)
      Vt[(ch * 8 + e) * 200 + row] = (u16)vreg[i][e];
  }

  float rmax[4] = {-3e38f, -3e38f, -3e38f, -3e38f};
  const int qbase = q0 + w * 16 + lk * 4;
#pragma unroll
  for (int f = 0; f < 12; ++f) {
    int kj = k0 + f * 16 + lrow;
    bool kok = (kj >= 0) && (kj < S_LEN);
#pragma unroll
    for (int j = 0; j < 4; ++j) {
      int qi = qbase + j;
      float v = sc[f][j];
      int dd = qi - kj;
      int ad = dd < 0 ? -dd : dd;
      v = (kok && ad <= halfw) ? v : -1e30f;
      sc[f][j] = v;
      rmax[j] = fmaxf(rmax[j], v);
    }
  }
#pragma unroll
  for (int j = 0; j < 4; ++j) {
    rmax[j] = fmaxf(rmax[j], __shfl_xor(rmax[j], 1, 16));
    rmax[j] = fmaxf(rmax[j], __shfl_xor(rmax[j], 2, 16));
    rmax[j] = fmaxf(rmax[j], __shfl_xor(rmax[j], 4, 16));
    rmax[j] = fmaxf(rmax[j], __shfl_xor(rmax[j], 8, 16));
  }
  float rsum[4] = {0.f, 0.f, 0.f, 0.f};
#pragma unroll
  for (int f = 0; f < 12; ++f)
#pragma unroll
    for (int j = 0; j < 4; ++j) {
      float e = __expf(sc[f][j] - rmax[j]);
      sc[f][j] = e;
      rsum[j] += e;
    }
#pragma unroll
  for (int j = 0; j < 4; ++j) {
    rsum[j] += __shfl_xor(rsum[j], 1, 16);
    rsum[j] += __shfl_xor(rsum[j], 2, 16);
    rsum[j] += __shfl_xor(rsum[j], 4, 16);
    rsum[j] += __shfl_xor(rsum[j], 8, 16);
  }
  float rinv[4];
#pragma unroll
  for (int j = 0; j < 4; ++j) rinv[j] = 1.0f / rsum[j];

  __syncthreads();

  u16* Ps = KP;
#pragma unroll
  for (int f = 0; f < 12; ++f)
#pragma unroll
    for (int j = 0; j < 4; ++j) {
      int prow = w * 16 + lk * 4 + j;
      Ps[prow * 200 + f * 16 + lrow] = f32_to_bf16(sc[f][j] * rinv[j]);
    }
  __syncthreads();

  f32x4 o[4] = {};
#pragma unroll
  for (int jt = 0; jt < 6; ++jt) {
    bf16x8 pa = *(const bf16x8*)(Ps + (w * 16 + lrow) * 200 + jt * 32 + lk * 8);
#pragma unroll
    for (int n = 0; n < 4; ++n) {
      bf16x8 vf = *(const bf16x8*)(Vt + (n * 16 + lrow) * 200 + jt * 32 + lk * 8);
      o[n] = __builtin_amdgcn_mfma_f32_16x16x32_bf16(pa, vf, o[n], 0, 0, 0);
    }
  }
#pragma unroll
  for (int n = 0; n < 4; ++n)
#pragma unroll
    for (int j = 0; j < 4; ++j) {
      int qi = q0 + w * 16 + lk * 4 + j;
      int d = n * 16 + lrow;
      ao[(size_t)(b * S_LEN + qi) * DMODEL + h * 64 + d] = f32_to_bf16(o[n][j]);
    }
}

// ---------------- launch ----------------
extern "C" void kernel_launch(void* const* d_in, const int* in_sizes, int n_in,
                              void* d_out, int out_size, void* d_ws, size_t ws_size,
                              hipStream_t stream) {
  (void)in_sizes; (void)n_in; (void)out_size; (void)ws_size;
  const float* x     = (const float*)d_in[0];
  const float* alpha = (const float*)d_in[1];
  const float* Wq    = (const float*)d_in[2];
  const float* bq    = (const float*)d_in[3];
  const float* Wk    = (const float*)d_in[4];
  const float* bk    = (const float*)d_in[5];
  const float* Wv    = (const float*)d_in[6];
  const float* bv    = (const float*)d_in[7];
  const float* W_o   = (const float*)d_in[8];
  const float* Wfc   = (const float*)d_in[9];
  const float* bfc   = (const float*)d_in[10];

  char* ws = (char*)d_ws;
  int* halfw  = (int*)ws;
  u16* xb     = (u16*)(ws + 256);
  u16* Wqkv_t = xb + (size_t)MROWS * DMODEL;
  u16* qkv    = Wqkv_t + (size_t)3 * DMODEL * DMODEL;   // [4096][3072]
  u16* ao     = qkv + (size_t)MROWS * QKV_LD;
  u16* Wc_t   = ao + (size_t)MROWS * DMODEL;

  hipLaunchKernelGGL(prep, dim3(5185), dim3(256), 0, stream,
                     x, xb, alpha, halfw, Wq, Wk, Wv, Wqkv_t, W_o, Wfc, Wc_t);
  hipLaunchKernelGGL(gemm_qkv, dim3(256), dim3(512), 0, stream,
                     xb, Wqkv_t, bq, bk, bv, qkv);
  hipLaunchKernelGGL(attn_win, dim3(S_LEN / 64, NHEAD, BATCH), dim3(256), 0, stream,
                     qkv, ao, halfw);
  hipLaunchKernelGGL(gemm_fc, dim3(256), dim3(256), 0, stream,
                     ao, Wc_t, bfc, (float*)d_out);
}

// Round 6
// 102.290 us; speedup vs baseline: 1.6615x; 1.6615x over previous
//
#include <hip/hip_runtime.h>
#include <hip/hip_bf16.h>
#include <stdint.h>
#include <stddef.h>

#define S_LEN 2048
#define DMODEL 1024
#define NHEAD 16
#define HDIM 64
#define BATCH 2
#define MROWS (BATCH * S_LEN) /* 4096 */
#define QKV_LD 3072

typedef unsigned short u16;
typedef __attribute__((ext_vector_type(8))) short bf16x8;
typedef __attribute__((ext_vector_type(4))) float f32x4;

__device__ inline u16 f32_to_bf16(float f) {
  union { float f; unsigned int u; } v; v.f = f;
  unsigned int u = v.u;
  unsigned int r = (u + 0x7fffu + ((u >> 16) & 1u)) >> 16;
  return (u16)r;
}

__device__ inline void gload16(const u16* g, u16* l) {
  __builtin_amdgcn_global_load_lds(
      (const __attribute__((address_space(1))) unsigned int*)g,
      (__attribute__((address_space(3))) unsigned int*)l, 16, 0, 0);
}

// ---------------- fused prologue: conv + window + W-transpose ----------------
// (Wc build is a SEPARATE kernel: fusing it here shares one register budget and
//  R5 showed the compiler caps VGPRs at ~44 for this low-LDS kernel -> acc[64]
//  spilled to scratch, 117 us. Keep only low-register paths fused.)
// blocks [0,2048): x->bf16 ; 2048: window ; [2049,5121): transpose
__global__ __launch_bounds__(256) void prep(const float* __restrict__ x, u16* __restrict__ xb,
                                            const float* __restrict__ alpha, int* __restrict__ halfw,
                                            const float* __restrict__ Wq, const float* __restrict__ Wk,
                                            const float* __restrict__ Wv, u16* __restrict__ Wt) {
  __shared__ float lds[32 * 33]; // 4224 B
  const int bid = blockIdx.x, tid = threadIdx.x;

  if (bid < 2048) {
    // ---- x -> bf16 ----
    size_t i = ((size_t)bid * 256 + tid) * 8;
    float4 v0 = *(const float4*)(x + i);
    float4 v1 = *(const float4*)(x + i + 4);
    bf16x8 r;
    r[0] = (short)f32_to_bf16(v0.x); r[1] = (short)f32_to_bf16(v0.y);
    r[2] = (short)f32_to_bf16(v0.z); r[3] = (short)f32_to_bf16(v0.w);
    r[4] = (short)f32_to_bf16(v1.x); r[5] = (short)f32_to_bf16(v1.y);
    r[6] = (short)f32_to_bf16(v1.z); r[7] = (short)f32_to_bf16(v1.w);
    *(bf16x8*)(xb + i) = r;
  } else if (bid == 2048) {
    // ---- dynamic window size ----
    float s = 0.f;
    for (int i = tid; i < BATCH * DMODEL; i += 256) {
      int b = i >> 10, d = i & 1023;
      size_t base = (size_t)b * S_LEN * DMODEL + d;
      float f1 = x[base + (size_t)(S_LEN - 1) * DMODEL];
      float f0 = x[base + (size_t)(S_LEN - 2) * DMODEL];
      s += fabsf(f1 - f0);
    }
#pragma unroll
    for (int m = 32; m >= 1; m >>= 1) s += __shfl_xor(s, m, 64);
    if ((tid & 63) == 0) lds[tid >> 6] = s;
    __syncthreads();
    if (tid == 0) {
      float total = lds[0] + lds[1] + lds[2] + lds[3];
      float mean = total / (float)(BATCH * DMODEL);
      float e1 = x[(size_t)(S_LEN - 1) * DMODEL];
      float e0 = x[(size_t)(S_LEN - 2) * DMODEL];
      float ew = fabsf(e1 - e0);
      float a = 1.f / (1.f + expf(-alpha[0]));
      float sig = a * mean + (1.f - a) * ew;
      float scale = 1.f / (1.f + expf(-sig));
      int wv = (int)floorf(24.f + 96.f * scale);
      *halfw = wv >> 1;
    }
  } else {
    // ---- transpose Wq/Wk/Wv -> bf16 [3][N][K] ----
    float (*tile)[33] = (float (*)[33])lds;
    const int r = bid - 2049;
    const int z = r >> 10, rem = r & 1023;
    const int k0 = (rem >> 5) * 32, n0 = (rem & 31) * 32;
    const float* W = z == 0 ? Wq : (z == 1 ? Wk : Wv);
    const int tx = tid & 31, ty = tid >> 5;
#pragma unroll
    for (int i = 0; i < 4; ++i)
      tile[ty + i * 8][tx] = W[(size_t)(k0 + ty + i * 8) * DMODEL + n0 + tx];
    __syncthreads();
    u16* o = Wt + (size_t)z * DMODEL * DMODEL;
#pragma unroll
    for (int i = 0; i < 4; ++i)
      o[(size_t)(n0 + ty + i * 8) * DMODEL + k0 + tx] = f32_to_bf16(tile[tx][ty + i * 8]);
  }
}

// ---------------- Wc = blockdiag(W_o) @ Wfc, stored transposed bf16 [N][K] ----------------
// R3-measured version: 32 KiB LDS keeps occupancy target low -> no VGPR spill.
__global__ __launch_bounds__(128) void build_wc(const float* __restrict__ W_o,
                                                const float* __restrict__ Wfc,
                                                u16* __restrict__ Wc_t) {
  __shared__ float lds[64 * 128];
  int nb = blockIdx.x, h = blockIdx.y, tx = threadIdx.x;
  int n0 = nb * 128;
#pragma unroll
  for (int c = 0; c < 64; ++c)
    lds[c * 128 + tx] = Wfc[(size_t)(h * 64 + c) * DMODEL + n0 + tx];
  __syncthreads();
  float acc[64];
#pragma unroll
  for (int d = 0; d < 64; ++d) acc[d] = 0.f;
  for (int c = 0; c < 64; ++c) {
    float wv = lds[c * 128 + tx];
#pragma unroll
    for (int d = 0; d < 64; ++d)
      acc[d] += W_o[(size_t)(h * 64 + d) * 64 + c] * wv;
  }
  u16 tmp[64];
#pragma unroll
  for (int d = 0; d < 64; ++d) tmp[d] = f32_to_bf16(acc[d]);
  u16* dst = Wc_t + (size_t)(n0 + tx) * DMODEL + h * 64;
#pragma unroll
  for (int q = 0; q < 8; ++q)
    *(bf16x8*)(dst + q * 8) = *(bf16x8*)(tmp + q * 8);
}

// ---------------- QKV GEMM: 256x192, BK=64, 8 waves, counted-vmcnt 4-phase ----------------
#define G1_ASZ (256 * 64) /* u16 elems */
#define G1_BSZ (192 * 64)
__global__ __launch_bounds__(512, 2) void gemm_qkv(
    const u16* __restrict__ A, const u16* __restrict__ Bt,
    const float* __restrict__ bq, const float* __restrict__ bk,
    const float* __restrict__ bv, u16* __restrict__ out) {
  __shared__ __align__(16) u16 smem[2][G1_ASZ + G1_BSZ]; // 112 KiB

  const int tid = threadIdx.x;
  const int l = tid & 63, w = tid >> 6;   // 8 waves
  const int wr = w >> 2, wc = w & 3;      // 2 x 4; wave tile 128x48
  const int lrow = l & 15, lk = l >> 4;

  // bn-major bijective XCD swizzle (grid 256): per-XCD B slice 768 KB, L2-resident
  const int xcd = blockIdx.x & 7;
  const int idx = blockIdx.x >> 3;
  const int bm = idx & 15;
  const int bn = xcd * 2 + (idx >> 4);
  const int rowA0 = bm * 256;
  const int colB0 = bn * 192;

  f32x4 acc[8][3] = {};

  auto stage = [&](int buf, int kt) {   // 7 gload16 per thread
    u16* As = smem[buf];
    u16* Bs = smem[buf] + G1_ASZ;
#pragma unroll
    for (int i = 0; i < 4; ++i) {
      int c = i * 512 + tid;
      int row = c >> 3, u = c & 7;
      const u16* g = A + (size_t)(rowA0 + row) * DMODEL + kt + ((u ^ (row & 7)) << 3);
      gload16(g, As + c * 8);
    }
#pragma unroll
    for (int i = 0; i < 3; ++i) {
      int c = i * 512 + tid;
      int row = c >> 3, u = c & 7;
      const u16* g = Bt + (size_t)(colB0 + row) * DMODEL + kt + ((u ^ (row & 7)) << 3);
      gload16(g, Bs + c * 8);
    }
  };

  stage(0, 0);

  int buf = 0;
#pragma unroll 1
  for (int t = 0; t < 16; ++t) {
    if (t < 15) {
      stage(buf ^ 1, (t + 1) * 64);
      asm volatile("s_waitcnt vmcnt(7)" ::: "memory");  // tile t landed; t+1 in flight
    } else {
      asm volatile("s_waitcnt vmcnt(0)" ::: "memory");
    }
    __builtin_amdgcn_s_barrier();
    asm volatile("" ::: "memory");      // no LDS-read hoisting above the barrier

    const u16* As = smem[buf];
    const u16* Bs = smem[buf] + G1_ASZ;
#pragma unroll
    for (int kk = 0; kk < 2; ++kk) {
      const int ksw = ((kk << 2) + lk);
      const int swz = ((ksw ^ (lrow & 7)) << 3);
      bf16x8 bg[3];
#pragma unroll
      for (int n = 0; n < 3; ++n) {
        int r = wc * 48 + n * 16 + lrow;
        bg[n] = *(const bf16x8*)(Bs + r * 64 + swz);
      }
#pragma unroll
      for (int mh = 0; mh < 2; ++mh) {
        bf16x8 af[4];
#pragma unroll
        for (int i = 0; i < 4; ++i) {
          int r = wr * 128 + (mh * 4 + i) * 16 + lrow;
          af[i] = *(const bf16x8*)(As + r * 64 + swz);
        }
        __builtin_amdgcn_s_setprio(1);
#pragma unroll
        for (int i = 0; i < 4; ++i)
#pragma unroll
          for (int n = 0; n < 3; ++n)
            acc[mh * 4 + i][n] =
                __builtin_amdgcn_mfma_f32_16x16x32_bf16(af[i], bg[n], acc[mh * 4 + i][n], 0, 0, 0);
        __builtin_amdgcn_s_setprio(0);
        __builtin_amdgcn_s_barrier();   // phase alignment; doubles as tile boundary on last phase
      }
    }
    asm volatile("" ::: "memory");
    buf ^= 1;
  }

  // epilogue: per-column bias; q columns also folded by 1/8
#pragma unroll
  for (int n = 0; n < 3; ++n) {
    int c = colB0 + wc * 48 + n * 16 + lrow;   // 0..3071
    float bias = (c < 1024) ? bq[c] : ((c < 2048) ? bk[c - 1024] : bv[c - 2048]);
    float mult = (c < 1024) ? 0.125f : 1.0f;
#pragma unroll
    for (int m = 0; m < 8; ++m) {
      int r0 = rowA0 + wr * 128 + m * 16 + lk * 4;
#pragma unroll
      for (int j = 0; j < 4; ++j)
        out[(size_t)(r0 + j) * QKV_LD + c] = f32_to_bf16((acc[m][n][j] + bias) * mult);
    }
  }
}

// ---------------- final FC GEMM: 128x128, BK=64, 4 waves, counted-vmcnt 2-phase ----------------
__global__ __launch_bounds__(256) void gemm_fc(const u16* __restrict__ A,
                                               const u16* __restrict__ Bt,
                                               const float* __restrict__ bias,
                                               float* __restrict__ out) {
  __shared__ __align__(16) u16 smem[2][256 * 64]; // 64 KiB

  const int tid = threadIdx.x;
  const int l = tid & 63, w = tid >> 6;   // 4 waves, 2x2
  const int wr = w >> 1, wc = w & 1;
  const int lrow = l & 15, lk = l >> 4;

  const int bn = blockIdx.x & 7;
  const int bm = blockIdx.x >> 3;
  const int rowA0 = bm * 128, colB0 = bn * 128;

  f32x4 acc[4][4] = {};

  auto stage = [&](int buf, int kt) {   // 8 gload16 per thread
    u16* As = smem[buf];
    u16* Bs = smem[buf] + 128 * 64;
#pragma unroll
    for (int i = 0; i < 4; ++i) {
      int c = i * 256 + tid;
      int row = c >> 3, u = c & 7;
      const u16* g = A + (size_t)(rowA0 + row) * DMODEL + kt + ((u ^ (row & 7)) << 3);
      gload16(g, As + c * 8);
    }
#pragma unroll
    for (int i = 0; i < 4; ++i) {
      int c = i * 256 + tid;
      int row = c >> 3, u = c & 7;
      const u16* g = Bt + (size_t)(colB0 + row) * DMODEL + kt + ((u ^ (row & 7)) << 3);
      gload16(g, Bs + c * 8);
    }
  };

  stage(0, 0);

  int buf = 0;
#pragma unroll 1
  for (int t = 0; t < 16; ++t) {
    if (t < 15) {
      stage(buf ^ 1, (t + 1) * 64);
      asm volatile("s_waitcnt vmcnt(8)" ::: "memory");
    } else {
      asm volatile("s_waitcnt vmcnt(0)" ::: "memory");
    }
    __builtin_amdgcn_s_barrier();
    asm volatile("" ::: "memory");

    const u16* As = smem[buf];
    const u16* Bs = smem[buf] + 128 * 64;
#pragma unroll
    for (int kk = 0; kk < 2; ++kk) {
      const int swz = ((((kk << 2) + lk) ^ (lrow & 7)) << 3);
      bf16x8 af[4], bg[4];
#pragma unroll
      for (int m = 0; m < 4; ++m) {
        int r = wr * 64 + m * 16 + lrow;
        af[m] = *(const bf16x8*)(As + r * 64 + swz);
      }
#pragma unroll
      for (int n = 0; n < 4; ++n) {
        int r = wc * 64 + n * 16 + lrow;
        bg[n] = *(const bf16x8*)(Bs + r * 64 + swz);
      }
      __builtin_amdgcn_s_setprio(1);
#pragma unroll
      for (int m = 0; m < 4; ++m)
#pragma unroll
        for (int n = 0; n < 4; ++n)
          acc[m][n] = __builtin_amdgcn_mfma_f32_16x16x32_bf16(af[m], bg[n], acc[m][n], 0, 0, 0);
      __builtin_amdgcn_s_setprio(0);
      __builtin_amdgcn_s_barrier();
    }
    asm volatile("" ::: "memory");
    buf ^= 1;
  }

#pragma unroll
  for (int n = 0; n < 4; ++n) {
    int c = colB0 + wc * 64 + n * 16 + lrow;
    float bv = bias[c];
#pragma unroll
    for (int m = 0; m < 4; ++m) {
      int r0 = rowA0 + wr * 64 + m * 16 + lk * 4;
#pragma unroll
      for (int j = 0; j < 4; ++j)
        out[(size_t)(r0 + j) * DMODEL + c] = acc[m][n][j] + bv;
    }
  }
}

// ---------------- banded attention: 64 queries x 192 keys per block ----------------
__global__ __launch_bounds__(256) void attn_win(const u16* __restrict__ qkv,
                                                u16* __restrict__ ao,
                                                const int* __restrict__ halfptr) {
  __shared__ __align__(16) u16 KP[12800];  // K [192][64] swizzled; reused as P [64][200]
  __shared__ __align__(16) u16 Vt[64 * 200]; // V transposed [d][key]
  const int tid = threadIdx.x, l = tid & 63, w = tid >> 6;
  const int lrow = l & 15, lk = l >> 4;
  const int q0 = blockIdx.x * 64, k0 = q0 - 64;
  const int h = blockIdx.y, b = blockIdx.z;
  const int halfw = *halfptr;

  const u16* qb = qkv;
  const u16* kb = qkv + 1024;
  const u16* vb = qkv + 2048;

  // K stage via global_load_lds (pre-swizzled source, linear dest). Out-of-band
  // rows read valid ws memory (finite garbage) and are always masked below.
#pragma unroll
  for (int i = 0; i < 6; ++i) {
    int c = i * 256 + tid;
    int row = c >> 3, u = c & 7;
    const u16* g = kb + (ptrdiff_t)((b * S_LEN + k0 + row) * QKV_LD + h * 64 + ((u ^ (row & 7)) << 3));
    gload16(g, KP + c * 8);
  }
  const int qrow = q0 + w * 16 + lrow;
  bf16x8 qf[2];
#pragma unroll
  for (int kk = 0; kk < 2; ++kk)
    qf[kk] = *(const bf16x8*)(qb + (ptrdiff_t)((b * S_LEN + qrow) * QKV_LD + h * 64 + kk * 32 + lk * 8));
  bf16x8 vreg[6];
#pragma unroll
  for (int i = 0; i < 6; ++i) {
    int c = i * 256 + tid;
    int row = c % 192, ch = c / 192;
    vreg[i] = *(const bf16x8*)(vb + (ptrdiff_t)((b * S_LEN + k0 + row) * QKV_LD + h * 64 + ch * 8));
  }

  asm volatile("s_waitcnt vmcnt(0)" ::: "memory");
  __syncthreads();

  f32x4 sc[12];
#pragma unroll
  for (int f = 0; f < 12; ++f) sc[f] = (f32x4){0.f, 0.f, 0.f, 0.f};
#pragma unroll
  for (int kk = 0; kk < 2; ++kk) {
#pragma unroll
    for (int f = 0; f < 12; ++f) {
      bf16x8 kf = *(const bf16x8*)(KP + (f * 16 + lrow) * 64 + ((((kk << 2) + lk) ^ (lrow & 7)) << 3));
      sc[f] = __builtin_amdgcn_mfma_f32_16x16x32_bf16(qf[kk], kf, sc[f], 0, 0, 0);
    }
  }

#pragma unroll
  for (int i = 0; i < 6; ++i) {
    int c = i * 256 + tid;
    int row = c % 192, ch = c / 192;
#pragma unroll
    for (int e = 0; e < 8; ++e)
      Vt[(ch * 8 + e) * 200 + row] = (u16)vreg[i][e];
  }

  float rmax[4] = {-3e38f, -3e38f, -3e38f, -3e38f};
  const int qbase = q0 + w * 16 + lk * 4;
#pragma unroll
  for (int f = 0; f < 12; ++f) {
    int kj = k0 + f * 16 + lrow;
    bool kok = (kj >= 0) && (kj < S_LEN);
#pragma unroll
    for (int j = 0; j < 4; ++j) {
      int qi = qbase + j;
      float v = sc[f][j];
      int dd = qi - kj;
      int ad = dd < 0 ? -dd : dd;
      v = (kok && ad <= halfw) ? v : -1e30f;
      sc[f][j] = v;
      rmax[j] = fmaxf(rmax[j], v);
    }
  }
#pragma unroll
  for (int j = 0; j < 4; ++j) {
    rmax[j] = fmaxf(rmax[j], __shfl_xor(rmax[j], 1, 16));
    rmax[j] = fmaxf(rmax[j], __shfl_xor(rmax[j], 2, 16));
    rmax[j] = fmaxf(rmax[j], __shfl_xor(rmax[j], 4, 16));
    rmax[j] = fmaxf(rmax[j], __shfl_xor(rmax[j], 8, 16));
  }
  float rsum[4] = {0.f, 0.f, 0.f, 0.f};
#pragma unroll
  for (int f = 0; f < 12; ++f)
#pragma unroll
    for (int j = 0; j < 4; ++j) {
      float e = __expf(sc[f][j] - rmax[j]);
      sc[f][j] = e;
      rsum[j] += e;
    }
#pragma unroll
  for (int j = 0; j < 4; ++j) {
    rsum[j] += __shfl_xor(rsum[j], 1, 16);
    rsum[j] += __shfl_xor(rsum[j], 2, 16);
    rsum[j] += __shfl_xor(rsum[j], 4, 16);
    rsum[j] += __shfl_xor(rsum[j], 8, 16);
  }
  float rinv[4];
#pragma unroll
  for (int j = 0; j < 4; ++j) rinv[j] = 1.0f / rsum[j];

  __syncthreads();

  u16* Ps = KP;
#pragma unroll
  for (int f = 0; f < 12; ++f)
#pragma unroll
    for (int j = 0; j < 4; ++j) {
      int prow = w * 16 + lk * 4 + j;
      Ps[prow * 200 + f * 16 + lrow] = f32_to_bf16(sc[f][j] * rinv[j]);
    }
  __syncthreads();

  f32x4 o[4] = {};
#pragma unroll
  for (int jt = 0; jt < 6; ++jt) {
    bf16x8 pa = *(const bf16x8*)(Ps + (w * 16 + lrow) * 200 + jt * 32 + lk * 8);
#pragma unroll
    for (int n = 0; n < 4; ++n) {
      bf16x8 vf = *(const bf16x8*)(Vt + (n * 16 + lrow) * 200 + jt * 32 + lk * 8);
      o[n] = __builtin_amdgcn_mfma_f32_16x16x32_bf16(pa, vf, o[n], 0, 0, 0);
    }
  }
#pragma unroll
  for (int n = 0; n < 4; ++n)
#pragma unroll
    for (int j = 0; j < 4; ++j) {
      int qi = q0 + w * 16 + lk * 4 + j;
      int d = n * 16 + lrow;
      ao[(size_t)(b * S_LEN + qi) * DMODEL + h * 64 + d] = f32_to_bf16(o[n][j]);
    }
}

// ---------------- launch ----------------
extern "C" void kernel_launch(void* const* d_in, const int* in_sizes, int n_in,
                              void* d_out, int out_size, void* d_ws, size_t ws_size,
                              hipStream_t stream) {
  (void)in_sizes; (void)n_in; (void)out_size; (void)ws_size;
  const float* x     = (const float*)d_in[0];
  const float* alpha = (const float*)d_in[1];
  const float* Wq    = (const float*)d_in[2];
  const float* bq    = (const float*)d_in[3];
  const float* Wk    = (const float*)d_in[4];
  const float* bk    = (const float*)d_in[5];
  const float* Wv    = (const float*)d_in[6];
  const float* bv    = (const float*)d_in[7];
  const float* W_o   = (const float*)d_in[8];
  const float* Wfc   = (const float*)d_in[9];
  const float* bfc   = (const float*)d_in[10];

  char* ws = (char*)d_ws;
  int* halfw  = (int*)ws;
  u16* xb     = (u16*)(ws + 256);
  u16* Wqkv_t = xb + (size_t)MROWS * DMODEL;
  u16* qkv    = Wqkv_t + (size_t)3 * DMODEL * DMODEL;   // [4096][3072]
  u16* ao     = qkv + (size_t)MROWS * QKV_LD;
  u16* Wc_t   = ao + (size_t)MROWS * DMODEL;

  hipLaunchKernelGGL(prep, dim3(5121), dim3(256), 0, stream,
                     x, xb, alpha, halfw, Wq, Wk, Wv, Wqkv_t);
  hipLaunchKernelGGL(build_wc, dim3(8, 16), dim3(128), 0, stream, W_o, Wfc, Wc_t);
  hipLaunchKernelGGL(gemm_qkv, dim3(256), dim3(512), 0, stream,
                     xb, Wqkv_t, bq, bk, bv, qkv);
  hipLaunchKernelGGL(attn_win, dim3(S_LEN / 64, NHEAD, BATCH), dim3(256), 0, stream,
                     qkv, ao, halfw);
  hipLaunchKernelGGL(gemm_fc, dim3(256), dim3(256), 0, stream,
                     ao, Wc_t, bfc, (float*)d_out);
}

// Round 7
// 100.342 us; speedup vs baseline: 1.6938x; 1.0194x over previous
//
#include <hip/hip_runtime.h>
#include <hip/hip_bf16.h>
#include <stdint.h>
#include <stddef.h>

#define S_LEN 2048
#define DMODEL 1024
#define NHEAD 16
#define HDIM 64
#define BATCH 2
#define MROWS (BATCH * S_LEN) /* 4096 */
#define QKV_LD 3072

typedef unsigned short u16;
typedef __attribute__((ext_vector_type(8))) short bf16x8;
typedef __attribute__((ext_vector_type(4))) float f32x4;

__device__ inline u16 f32_to_bf16(float f) {
  union { float f; unsigned int u; } v; v.f = f;
  unsigned int u = v.u;
  unsigned int r = (u + 0x7fffu + ((u >> 16) & 1u)) >> 16;
  return (u16)r;
}

__device__ inline void gload16(const u16* g, u16* l) {
  __builtin_amdgcn_global_load_lds(
      (const __attribute__((address_space(1))) unsigned int*)g,
      (__attribute__((address_space(3))) unsigned int*)l, 16, 0, 0);
}

// ---------------- fused prologue: conv + window + W-transpose ----------------
// blocks [0,2048): x->bf16 ; 2048: window ; [2049,5121): transpose
__global__ __launch_bounds__(256) void prep(const float* __restrict__ x, u16* __restrict__ xb,
                                            const float* __restrict__ alpha, int* __restrict__ halfw,
                                            const float* __restrict__ Wq, const float* __restrict__ Wk,
                                            const float* __restrict__ Wv, u16* __restrict__ Wt) {
  __shared__ float lds[32 * 33]; // 4224 B
  const int bid = blockIdx.x, tid = threadIdx.x;

  if (bid < 2048) {
    size_t i = ((size_t)bid * 256 + tid) * 8;
    float4 v0 = *(const float4*)(x + i);
    float4 v1 = *(const float4*)(x + i + 4);
    bf16x8 r;
    r[0] = (short)f32_to_bf16(v0.x); r[1] = (short)f32_to_bf16(v0.y);
    r[2] = (short)f32_to_bf16(v0.z); r[3] = (short)f32_to_bf16(v0.w);
    r[4] = (short)f32_to_bf16(v1.x); r[5] = (short)f32_to_bf16(v1.y);
    r[6] = (short)f32_to_bf16(v1.z); r[7] = (short)f32_to_bf16(v1.w);
    *(bf16x8*)(xb + i) = r;
  } else if (bid == 2048) {
    float s = 0.f;
    for (int i = tid; i < BATCH * DMODEL; i += 256) {
      int b = i >> 10, d = i & 1023;
      size_t base = (size_t)b * S_LEN * DMODEL + d;
      float f1 = x[base + (size_t)(S_LEN - 1) * DMODEL];
      float f0 = x[base + (size_t)(S_LEN - 2) * DMODEL];
      s += fabsf(f1 - f0);
    }
#pragma unroll
    for (int m = 32; m >= 1; m >>= 1) s += __shfl_xor(s, m, 64);
    if ((tid & 63) == 0) lds[tid >> 6] = s;
    __syncthreads();
    if (tid == 0) {
      float total = lds[0] + lds[1] + lds[2] + lds[3];
      float mean = total / (float)(BATCH * DMODEL);
      float e1 = x[(size_t)(S_LEN - 1) * DMODEL];
      float e0 = x[(size_t)(S_LEN - 2) * DMODEL];
      float ew = fabsf(e1 - e0);
      float a = 1.f / (1.f + expf(-alpha[0]));
      float sig = a * mean + (1.f - a) * ew;
      float scale = 1.f / (1.f + expf(-sig));
      int wv = (int)floorf(24.f + 96.f * scale);
      *halfw = wv >> 1;
    }
  } else {
    float (*tile)[33] = (float (*)[33])lds;
    const int r = bid - 2049;
    const int z = r >> 10, rem = r & 1023;
    const int k0 = (rem >> 5) * 32, n0 = (rem & 31) * 32;
    const float* W = z == 0 ? Wq : (z == 1 ? Wk : Wv);
    const int tx = tid & 31, ty = tid >> 5;
#pragma unroll
    for (int i = 0; i < 4; ++i)
      tile[ty + i * 8][tx] = W[(size_t)(k0 + ty + i * 8) * DMODEL + n0 + tx];
    __syncthreads();
    u16* o = Wt + (size_t)z * DMODEL * DMODEL;
#pragma unroll
    for (int i = 0; i < 4; ++i)
      o[(size_t)(n0 + ty + i * 8) * DMODEL + k0 + tx] = f32_to_bf16(tile[tx][ty + i * 8]);
  }
}

// ---------------- Wc = blockdiag(W_o) @ Wfc, stored transposed bf16 [N][K] ----------------
// 32 KiB LDS keeps the VGPR budget generous -> acc[64] stays in registers (R5 lesson).
__global__ __launch_bounds__(128) void build_wc(const float* __restrict__ W_o,
                                                const float* __restrict__ Wfc,
                                                u16* __restrict__ Wc_t) {
  __shared__ float lds[64 * 128];
  int nb = blockIdx.x, h = blockIdx.y, tx = threadIdx.x;
  int n0 = nb * 128;
#pragma unroll
  for (int c = 0; c < 64; ++c)
    lds[c * 128 + tx] = Wfc[(size_t)(h * 64 + c) * DMODEL + n0 + tx];
  __syncthreads();
  float acc[64];
#pragma unroll
  for (int d = 0; d < 64; ++d) acc[d] = 0.f;
  for (int c = 0; c < 64; ++c) {
    float wv = lds[c * 128 + tx];
#pragma unroll
    for (int d = 0; d < 64; ++d)
      acc[d] += W_o[(size_t)(h * 64 + d) * 64 + c] * wv;
  }
  u16 tmp[64];
#pragma unroll
  for (int d = 0; d < 64; ++d) tmp[d] = f32_to_bf16(acc[d]);
  u16* dst = Wc_t + (size_t)(n0 + tx) * DMODEL + h * 64;
#pragma unroll
  for (int q = 0; q < 8; ++q)
    *(bf16x8*)(dst + q * 8) = *(bf16x8*)(tmp + q * 8);
}

// ---------------- QKV GEMM: 256x192, BK=64, 8 waves, counted-vmcnt, 2 barriers/tile ----------------
// R6 post-mortem: per-12-MFMA phase barriers serialized ds_read vs MFMA (MfmaUtil 23%).
// Now the whole tile's 22 ds_read + 48 MFMA form ONE region for the compiler scheduler.
#define G1_ASZ (256 * 64) /* u16 elems */
#define G1_BSZ (192 * 64)
__global__ __launch_bounds__(512, 2) void gemm_qkv(
    const u16* __restrict__ A, const u16* __restrict__ Bt,
    const float* __restrict__ bq, const float* __restrict__ bk,
    const float* __restrict__ bv, u16* __restrict__ out) {
  __shared__ __align__(16) u16 smem[2][G1_ASZ + G1_BSZ]; // 112 KiB

  const int tid = threadIdx.x;
  const int l = tid & 63, w = tid >> 6;   // 8 waves
  const int wr = w >> 2, wc = w & 3;      // 2 x 4; wave tile 128x48
  const int lrow = l & 15, lk = l >> 4;

  // bn-major bijective XCD swizzle (grid 256): per-XCD B slice 768 KB, L2-resident
  const int xcd = blockIdx.x & 7;
  const int idx = blockIdx.x >> 3;
  const int bm = idx & 15;
  const int bn = xcd * 2 + (idx >> 4);
  const int rowA0 = bm * 256;
  const int colB0 = bn * 192;

  f32x4 acc[8][3] = {};

  auto stage = [&](int buf, int kt) {   // 7 gload16 per thread
    u16* As = smem[buf];
    u16* Bs = smem[buf] + G1_ASZ;
#pragma unroll
    for (int i = 0; i < 4; ++i) {
      int c = i * 512 + tid;
      int row = c >> 3, u = c & 7;
      const u16* g = A + (size_t)(rowA0 + row) * DMODEL + kt + ((u ^ (row & 7)) << 3);
      gload16(g, As + c * 8);
    }
#pragma unroll
    for (int i = 0; i < 3; ++i) {
      int c = i * 512 + tid;
      int row = c >> 3, u = c & 7;
      const u16* g = Bt + (size_t)(colB0 + row) * DMODEL + kt + ((u ^ (row & 7)) << 3);
      gload16(g, Bs + c * 8);
    }
  };

  stage(0, 0);

  int buf = 0;
#pragma unroll 1
  for (int t = 0; t < 16; ++t) {
    // barrier #1: every wave's previous-tile MFMAs done => its reads of buf^1 done
    __builtin_amdgcn_s_barrier();
    if (t < 15) {
      stage(buf ^ 1, (t + 1) * 64);                     // overwrite-safe after barrier #1
      asm volatile("s_waitcnt vmcnt(7)" ::: "memory");  // tile t landed; t+1 stays in flight
    } else {
      asm volatile("s_waitcnt vmcnt(0)" ::: "memory");
    }
    __builtin_amdgcn_s_barrier();                        // tile t visible to all waves
    asm volatile("" ::: "memory");

    const u16* As = smem[buf];
    const u16* Bs = smem[buf] + G1_ASZ;
    __builtin_amdgcn_s_setprio(1);
#pragma unroll
    for (int kk = 0; kk < 2; ++kk) {
      const int swz = ((((kk << 2) + lk) ^ (lrow & 7)) << 3);
      bf16x8 bg[3], af[8];
#pragma unroll
      for (int n = 0; n < 3; ++n)
        bg[n] = *(const bf16x8*)(Bs + (wc * 48 + n * 16 + lrow) * 64 + swz);
#pragma unroll
      for (int m = 0; m < 8; ++m)
        af[m] = *(const bf16x8*)(As + (wr * 128 + m * 16 + lrow) * 64 + swz);
#pragma unroll
      for (int m = 0; m < 8; ++m)
#pragma unroll
        for (int n = 0; n < 3; ++n)
          acc[m][n] = __builtin_amdgcn_mfma_f32_16x16x32_bf16(af[m], bg[n], acc[m][n], 0, 0, 0);
    }
    __builtin_amdgcn_s_setprio(0);
    buf ^= 1;
  }

  // epilogue: per-column bias; q columns also folded by 1/8
#pragma unroll
  for (int n = 0; n < 3; ++n) {
    int c = colB0 + wc * 48 + n * 16 + lrow;   // 0..3071
    float bias = (c < 1024) ? bq[c] : ((c < 2048) ? bk[c - 1024] : bv[c - 2048]);
    float mult = (c < 1024) ? 0.125f : 1.0f;
#pragma unroll
    for (int m = 0; m < 8; ++m) {
      int r0 = rowA0 + wr * 128 + m * 16 + lk * 4;
#pragma unroll
      for (int j = 0; j < 4; ++j)
        out[(size_t)(r0 + j) * QKV_LD + c] = f32_to_bf16((acc[m][n][j] + bias) * mult);
    }
  }
}

// ---------------- final FC GEMM: 128x128, BK=64, 4 waves, counted-vmcnt, 2 barriers/tile ----------------
__global__ __launch_bounds__(256) void gemm_fc(const u16* __restrict__ A,
                                               const u16* __restrict__ Bt,
                                               const float* __restrict__ bias,
                                               float* __restrict__ out) {
  __shared__ __align__(16) u16 smem[2][256 * 64]; // 64 KiB

  const int tid = threadIdx.x;
  const int l = tid & 63, w = tid >> 6;   // 4 waves, 2x2
  const int wr = w >> 1, wc = w & 1;
  const int lrow = l & 15, lk = l >> 4;

  const int bn = blockIdx.x & 7;
  const int bm = blockIdx.x >> 3;
  const int rowA0 = bm * 128, colB0 = bn * 128;

  f32x4 acc[4][4] = {};

  auto stage = [&](int buf, int kt) {   // 8 gload16 per thread
    u16* As = smem[buf];
    u16* Bs = smem[buf] + 128 * 64;
#pragma unroll
    for (int i = 0; i < 4; ++i) {
      int c = i * 256 + tid;
      int row = c >> 3, u = c & 7;
      const u16* g = A + (size_t)(rowA0 + row) * DMODEL + kt + ((u ^ (row & 7)) << 3);
      gload16(g, As + c * 8);
    }
#pragma unroll
    for (int i = 0; i < 4; ++i) {
      int c = i * 256 + tid;
      int row = c >> 3, u = c & 7;
      const u16* g = Bt + (size_t)(colB0 + row) * DMODEL + kt + ((u ^ (row & 7)) << 3);
      gload16(g, Bs + c * 8);
    }
  };

  stage(0, 0);

  int buf = 0;
#pragma unroll 1
  for (int t = 0; t < 16; ++t) {
    __builtin_amdgcn_s_barrier();
    if (t < 15) {
      stage(buf ^ 1, (t + 1) * 64);
      asm volatile("s_waitcnt vmcnt(8)" ::: "memory");
    } else {
      asm volatile("s_waitcnt vmcnt(0)" ::: "memory");
    }
    __builtin_amdgcn_s_barrier();
    asm volatile("" ::: "memory");

    const u16* As = smem[buf];
    const u16* Bs = smem[buf] + 128 * 64;
    __builtin_amdgcn_s_setprio(1);
#pragma unroll
    for (int kk = 0; kk < 2; ++kk) {
      const int swz = ((((kk << 2) + lk) ^ (lrow & 7)) << 3);
      bf16x8 af[4], bg[4];
#pragma unroll
      for (int m = 0; m < 4; ++m)
        af[m] = *(const bf16x8*)(As + (wr * 64 + m * 16 + lrow) * 64 + swz);
#pragma unroll
      for (int n = 0; n < 4; ++n)
        bg[n] = *(const bf16x8*)(Bs + (wc * 64 + n * 16 + lrow) * 64 + swz);
#pragma unroll
      for (int m = 0; m < 4; ++m)
#pragma unroll
        for (int n = 0; n < 4; ++n)
          acc[m][n] = __builtin_amdgcn_mfma_f32_16x16x32_bf16(af[m], bg[n], acc[m][n], 0, 0, 0);
    }
    __builtin_amdgcn_s_setprio(0);
    buf ^= 1;
  }

#pragma unroll
  for (int n = 0; n < 4; ++n) {
    int c = colB0 + wc * 64 + n * 16 + lrow;
    float bv = bias[c];
#pragma unroll
    for (int m = 0; m < 4; ++m) {
      int r0 = rowA0 + wr * 64 + m * 16 + lk * 4;
#pragma unroll
      for (int j = 0; j < 4; ++j)
        out[(size_t)(r0 + j) * DMODEL + c] = acc[m][n][j] + bv;
    }
  }
}

// ---------------- banded attention: 64 queries x 192 keys per block ----------------
__global__ __launch_bounds__(256) void attn_win(const u16* __restrict__ qkv,
                                                u16* __restrict__ ao,
                                                const int* __restrict__ halfptr) {
  __shared__ __align__(16) u16 KP[12800];  // K [192][64] swizzled; reused as P [64][200]
  __shared__ __align__(16) u16 Vt[64 * 200]; // V transposed [d][key]
  const int tid = threadIdx.x, l = tid & 63, w = tid >> 6;
  const int lrow = l & 15, lk = l >> 4;
  const int q0 = blockIdx.x * 64, k0 = q0 - 64;
  const int h = blockIdx.y, b = blockIdx.z;
  const int halfw = *halfptr;

  const u16* qb = qkv;
  const u16* kb = qkv + 1024;
  const u16* vb = qkv + 2048;

#pragma unroll
  for (int i = 0; i < 6; ++i) {
    int c = i * 256 + tid;
    int row = c >> 3, u = c & 7;
    const u16* g = kb + (ptrdiff_t)((b * S_LEN + k0 + row) * QKV_LD + h * 64 + ((u ^ (row & 7)) << 3));
    gload16(g, KP + c * 8);
  }
  const int qrow = q0 + w * 16 + lrow;
  bf16x8 qf[2];
#pragma unroll
  for (int kk = 0; kk < 2; ++kk)
    qf[kk] = *(const bf16x8*)(qb + (ptrdiff_t)((b * S_LEN + qrow) * QKV_LD + h * 64 + kk * 32 + lk * 8));
  bf16x8 vreg[6];
#pragma unroll
  for (int i = 0; i < 6; ++i) {
    int c = i * 256 + tid;
    int row = c % 192, ch = c / 192;
    vreg[i] = *(const bf16x8*)(vb + (ptrdiff_t)((b * S_LEN + k0 + row) * QKV_LD + h * 64 + ch * 8));
  }

  asm volatile("s_waitcnt vmcnt(0)" ::: "memory");
  __syncthreads();

  f32x4 sc[12];
#pragma unroll
  for (int f = 0; f < 12; ++f) sc[f] = (f32x4){0.f, 0.f, 0.f, 0.f};
#pragma unroll
  for (int kk = 0; kk < 2; ++kk) {
#pragma unroll
    for (int f = 0; f < 12; ++f) {
      bf16x8 kf = *(const bf16x8*)(KP + (f * 16 + lrow) * 64 + ((((kk << 2) + lk) ^ (lrow & 7)) << 3));
      sc[f] = __builtin_amdgcn_mfma_f32_16x16x32_bf16(qf[kk], kf, sc[f], 0, 0, 0);
    }
  }

#pragma unroll
  for (int i = 0; i < 6; ++i) {
    int c = i * 256 + tid;
    int row = c % 192, ch = c / 192;
#pragma unroll
    for (int e = 0; e < 8; ++e)
      Vt[(ch * 8 + e) * 200 + row] = (u16)vreg[i][e];
  }

  float rmax[4] = {-3e38f, -3e38f, -3e38f, -3e38f};
  const int qbase = q0 + w * 16 + lk * 4;
#pragma unroll
  for (int f = 0; f < 12; ++f) {
    int kj = k0 + f * 16 + lrow;
    bool kok = (kj >= 0) && (kj < S_LEN);
#pragma unroll
    for (int j = 0; j < 4; ++j) {
      int qi = qbase + j;
      float v = sc[f][j];
      int dd = qi - kj;
      int ad = dd < 0 ? -dd : dd;
      v = (kok && ad <= halfw) ? v : -1e30f;
      sc[f][j] = v;
      rmax[j] = fmaxf(rmax[j], v);
    }
  }
#pragma unroll
  for (int j = 0; j < 4; ++j) {
    rmax[j] = fmaxf(rmax[j], __shfl_xor(rmax[j], 1, 16));
    rmax[j] = fmaxf(rmax[j], __shfl_xor(rmax[j], 2, 16));
    rmax[j] = fmaxf(rmax[j], __shfl_xor(rmax[j], 4, 16));
    rmax[j] = fmaxf(rmax[j], __shfl_xor(rmax[j], 8, 16));
  }
  float rsum[4] = {0.f, 0.f, 0.f, 0.f};
#pragma unroll
  for (int f = 0; f < 12; ++f)
#pragma unroll
    for (int j = 0; j < 4; ++j) {
      float e = __expf(sc[f][j] - rmax[j]);
      sc[f][j] = e;
      rsum[j] += e;
    }
#pragma unroll
  for (int j = 0; j < 4; ++j) {
    rsum[j] += __shfl_xor(rsum[j], 1, 16);
    rsum[j] += __shfl_xor(rsum[j], 2, 16);
    rsum[j] += __shfl_xor(rsum[j], 4, 16);
    rsum[j] += __shfl_xor(rsum[j], 8, 16);
  }
  float rinv[4];
#pragma unroll
  for (int j = 0; j < 4; ++j) rinv[j] = 1.0f / rsum[j];

  __syncthreads();

  u16* Ps = KP;
#pragma unroll
  for (int f = 0; f < 12; ++f)
#pragma unroll
    for (int j = 0; j < 4; ++j) {
      int prow = w * 16 + lk * 4 + j;
      Ps[prow * 200 + f * 16 + lrow] = f32_to_bf16(sc[f][j] * rinv[j]);
    }
  __syncthreads();

  f32x4 o[4] = {};
#pragma unroll
  for (int jt = 0; jt < 6; ++jt) {
    bf16x8 pa = *(const bf16x8*)(Ps + (w * 16 + lrow) * 200 + jt * 32 + lk * 8);
#pragma unroll
    for (int n = 0; n < 4; ++n) {
      bf16x8 vf = *(const bf16x8*)(Vt + (n * 16 + lrow) * 200 + jt * 32 + lk * 8);
      o[n] = __builtin_amdgcn_mfma_f32_16x16x32_bf16(pa, vf, o[n], 0, 0, 0);
    }
  }
#pragma unroll
  for (int n = 0; n < 4; ++n)
#pragma unroll
    for (int j = 0; j < 4; ++j) {
      int qi = q0 + w * 16 + lk * 4 + j;
      int d = n * 16 + lrow;
      ao[(size_t)(b * S_LEN + qi) * DMODEL + h * 64 + d] = f32_to_bf16(o[n][j]);
    }
}

// ---------------- launch ----------------
extern "C" void kernel_launch(void* const* d_in, const int* in_sizes, int n_in,
                              void* d_out, int out_size, void* d_ws, size_t ws_size,
                              hipStream_t stream) {
  (void)in_sizes; (void)n_in; (void)out_size; (void)ws_size;
  const float* x     = (const float*)d_in[0];
  const float* alpha = (const float*)d_in[1];
  const float* Wq    = (const float*)d_in[2];
  const float* bq    = (const float*)d_in[3];
  const float* Wk    = (const float*)d_in[4];
  const float* bk    = (const float*)d_in[5];
  const float* Wv    = (const float*)d_in[6];
  const float* bv    = (const float*)d_in[7];
  const float* W_o   = (const float*)d_in[8];
  const float* Wfc   = (const float*)d_in[9];
  const float* bfc   = (const float*)d_in[10];

  char* ws = (char*)d_ws;
  int* halfw  = (int*)ws;
  u16* xb     = (u16*)(ws + 256);
  u16* Wqkv_t = xb + (size_t)MROWS * DMODEL;
  u16* qkv    = Wqkv_t + (size_t)3 * DMODEL * DMODEL;   // [4096][3072]
  u16* ao     = qkv + (size_t)MROWS * QKV_LD;
  u16* Wc_t   = ao + (size_t)MROWS * DMODEL;

  hipLaunchKernelGGL(prep, dim3(5121), dim3(256), 0, stream,
                     x, xb, alpha, halfw, Wq, Wk, Wv, Wqkv_t);
  hipLaunchKernelGGL(build_wc, dim3(8, 16), dim3(128), 0, stream, W_o, Wfc, Wc_t);
  hipLaunchKernelGGL(gemm_qkv, dim3(256), dim3(512), 0, stream,
                     xb, Wqkv_t, bq, bk, bv, qkv);
  hipLaunchKernelGGL(attn_win, dim3(S_LEN / 64, NHEAD, BATCH), dim3(256), 0, stream,
                     qkv, ao, halfw);
  hipLaunchKernelGGL(gemm_fc, dim3(256), dim3(256), 0, stream,
                     ao, Wc_t, bfc, (float*)d_out);
}